// Round 1
// baseline (160.336 us; speedup 1.0000x reference)
//
#include <hip/hip_runtime.h>
#include <math.h>

// TurboQuantValue: per-128-row sign-flip -> FWHT -> 4-bit quant/dequant -> FWHT -> sign-flip.
// Memory-bound streaming kernel: 2 rows per wave, float4 per lane.

#define DIM 128
__device__ __constant__ const float kInvSqrtDim = 0.08838834764831845f;  // 1/sqrt(128)
__device__ __constant__ const float kSqrtDim    = 11.313708498984761f;   // sqrt(128)

__device__ __forceinline__ void fwht128(float& a0, float& a1, float& a2, float& a3, int lane) {
    // bit 0 (in-register pairs)
    float t;
    t = a0; a0 = t + a1; a1 = t - a1;
    t = a2; a2 = t + a3; a3 = t - a3;
    // bit 1 (in-register pairs)
    t = a0; a0 = t + a2; a2 = t - a2;
    t = a1; a1 = t + a3; a3 = t - a3;
    // bits 2..6 -> cross-lane butterflies, masks 1..16 (stay within 32-lane half)
#pragma unroll
    for (int m = 1; m <= 16; m <<= 1) {
        float sgn = (lane & m) ? -1.0f : 1.0f;
        float b0 = __shfl_xor(a0, m, 64);
        float b1 = __shfl_xor(a1, m, 64);
        float b2 = __shfl_xor(a2, m, 64);
        float b3 = __shfl_xor(a3, m, 64);
        a0 = fmaf(sgn, a0, b0);
        a1 = fmaf(sgn, a1, b1);
        a2 = fmaf(sgn, a2, b2);
        a3 = fmaf(sgn, a3, b3);
    }
    a0 *= kInvSqrtDim; a1 *= kInvSqrtDim; a2 *= kInvSqrtDim; a3 *= kInvSqrtDim;
}

__global__ __launch_bounds__(256) void turboquant_kernel(
    const float* __restrict__ x, const float* __restrict__ signs,
    float* __restrict__ out, long long nrows) {
    const int lane = threadIdx.x & 63;
    const int l32  = lane & 31;
    const int half = lane >> 5;  // 0 or 1: which row of the pair this lane works on

    // sign vector for this lane's 4 elements (element index = 4*l32 + j)
    float4 sv = *reinterpret_cast<const float4*>(signs + l32 * 4);
    const float s0 = (sv.x >= 0.5f) ? 1.0f : -1.0f;
    const float s1 = (sv.y >= 0.5f) ? 1.0f : -1.0f;
    const float s2 = (sv.z >= 0.5f) ? 1.0f : -1.0f;
    const float s3 = (sv.w >= 0.5f) ? 1.0f : -1.0f;

    const long long waves_total = (long long)gridDim.x * (blockDim.x >> 6);
    const long long wave_id = (long long)blockIdx.x * (blockDim.x >> 6) + (threadIdx.x >> 6);

    const float EPS = 1e-8f;
    const float C   = 0.456f;

    for (long long rp = wave_id; rp * 2 < nrows; rp += waves_total) {
        const long long row = rp * 2 + half;
        if (row >= nrows) break;
        const float4 v = *reinterpret_cast<const float4*>(x + row * DIM + l32 * 4);

        float a0 = v.x * s0, a1 = v.y * s1, a2 = v.z * s2, a3 = v.w * s3;
        fwht128(a0, a1, a2, a3, lane);

        // fused reductions over the 32-lane group (one row): sum r^2 and sum |r|
        float ss = fmaf(a0, a0, fmaf(a1, a1, fmaf(a2, a2, a3 * a3)));
        float sa = fabsf(a0) + fabsf(a1) + fabsf(a2) + fabsf(a3);
#pragma unroll
        for (int m = 1; m <= 16; m <<= 1) {
            ss += __shfl_xor(ss, m, 64);
            sa += __shfl_xor(sa, m, 64);
        }

        const float norm   = sqrtf(ss);
        const float uscale = kSqrtDim / (norm + EPS);          // u = r * uscale
        const float scales = C * (sa * uscale) * (1.0f / 128.0f);  // C * mean|u|
        const float sden   = scales + EPS;
        const float rscale = scales * (norm * (1.0f / 11.313708498984761f));

        // quantize + dequantize (pack/unpack is identity): q = clip(round(u/sden), -8, 7)
        a0 = fminf(fmaxf(rintf((a0 * uscale) / sden), -8.0f), 7.0f) * rscale;
        a1 = fminf(fmaxf(rintf((a1 * uscale) / sden), -8.0f), 7.0f) * rscale;
        a2 = fminf(fmaxf(rintf((a2 * uscale) / sden), -8.0f), 7.0f) * rscale;
        a3 = fminf(fmaxf(rintf((a3 * uscale) / sden), -8.0f), 7.0f) * rscale;

        // inverse transform (FWHT is involutive) + sign-flip
        fwht128(a0, a1, a2, a3, lane);
        float4 o;
        o.x = a0 * s0; o.y = a1 * s1; o.z = a2 * s2; o.w = a3 * s3;
        *reinterpret_cast<float4*>(out + row * DIM + l32 * 4) = o;
    }
}

extern "C" void kernel_launch(void* const* d_in, const int* in_sizes, int n_in,
                              void* d_out, int out_size, void* d_ws, size_t ws_size,
                              hipStream_t stream) {
    const float* x     = (const float*)d_in[0];
    const float* signs = (const float*)d_in[1];
    float* out = (float*)d_out;
    const long long nrows = (long long)in_sizes[0] / DIM;
    const int blocks = 2048;  // grid-stride; 256 threads = 4 waves/block
    turboquant_kernel<<<blocks, 256, 0, stream>>>(x, signs, out, nrows);
}

// Round 2
// 150.031 us; speedup vs baseline: 1.0687x; 1.0687x over previous
//
#include <hip/hip_runtime.h>
#include <math.h>

// TurboQuantValue: sign-flip -> FWHT128 -> 4-bit quant/dequant -> FWHT128 -> sign-flip.
// Layout: 16 consecutive elems per lane, 8 lanes per row, 8 rows per wave64.
// FWHT bits 0-3 in-register, bits 4-6 via ds_swizzle (lane xor 1,2,4).
// All 1/sqrt(128) normalizations folded into per-row scalars.

#define DIM 128
#define INV_SQRT_DIM 0.08838834764831845f

// compile-time-pattern lane XOR within 32-lane groups (BitMode ds_swizzle)
template <int M>
__device__ __forceinline__ float swz_xor(float v) {
    int r = __builtin_amdgcn_ds_swizzle(__float_as_int(v), (M << 10) | 0x1F);
    return __int_as_float(r);
}

__device__ __forceinline__ float sflip(float v, unsigned sbits, int k) {
    unsigned m = ((sbits >> k) & 1u) << 31;
    return __int_as_float(__float_as_int(v) ^ m);
}

// raw (unnormalized) FWHT over 128 elems: 16/lane in-register + 3 cross-lane stages
__device__ __forceinline__ void fwht_raw(float a[16], int lane) {
#pragma unroll
    for (int h = 1; h < 16; h <<= 1) {
#pragma unroll
        for (int i = 0; i < 16; ++i) {
            if (!(i & h)) {
                float u = a[i], w = a[i + h];
                a[i] = u + w;
                a[i + h] = u - w;
            }
        }
    }
    // cross-lane: element bit 4,5,6 <-> lane bit 0,1,2
    {
        const float sgn = (lane & 1) ? -1.0f : 1.0f;
#pragma unroll
        for (int i = 0; i < 16; ++i) { float b = swz_xor<1>(a[i]); a[i] = fmaf(sgn, a[i], b); }
    }
    {
        const float sgn = (lane & 2) ? -1.0f : 1.0f;
#pragma unroll
        for (int i = 0; i < 16; ++i) { float b = swz_xor<2>(a[i]); a[i] = fmaf(sgn, a[i], b); }
    }
    {
        const float sgn = (lane & 4) ? -1.0f : 1.0f;
#pragma unroll
        for (int i = 0; i < 16; ++i) { float b = swz_xor<4>(a[i]); a[i] = fmaf(sgn, a[i], b); }
    }
}

__global__ __launch_bounds__(256) void turboquant_kernel(
    const float* __restrict__ x, const float* __restrict__ signs,
    float* __restrict__ out, long long nrows) {
    const int lane = threadIdx.x & 63;
    const int j    = lane & 7;   // lane within row (owns elems j*16 .. j*16+15)
    const int rsub = lane >> 3;  // row within the wave's 8-row group

    // per-lane sign bitmask (1 = negative) for elements j*16+k
    unsigned sbits = 0;
    const float4* sp = reinterpret_cast<const float4*>(signs + j * 16);
#pragma unroll
    for (int k4 = 0; k4 < 4; ++k4) {
        float4 sv = sp[k4];
        if (sv.x < 0.5f) sbits |= 1u << (k4 * 4 + 0);
        if (sv.y < 0.5f) sbits |= 1u << (k4 * 4 + 1);
        if (sv.z < 0.5f) sbits |= 1u << (k4 * 4 + 2);
        if (sv.w < 0.5f) sbits |= 1u << (k4 * 4 + 3);
    }

    const long long waves_total = (long long)gridDim.x * 4;
    const long long wid = (long long)blockIdx.x * 4 + (threadIdx.x >> 6);

    for (long long it = wid; it * 8 < nrows; it += waves_total) {
        const long long row = it * 8 + rsub;
        const float* rp = x + row * DIM + j * 16;
        float4 v0 = *reinterpret_cast<const float4*>(rp);
        float4 v1 = *reinterpret_cast<const float4*>(rp + 4);
        float4 v2 = *reinterpret_cast<const float4*>(rp + 8);
        float4 v3 = *reinterpret_cast<const float4*>(rp + 12);

        float a[16];
        a[0]  = sflip(v0.x, sbits, 0);  a[1]  = sflip(v0.y, sbits, 1);
        a[2]  = sflip(v0.z, sbits, 2);  a[3]  = sflip(v0.w, sbits, 3);
        a[4]  = sflip(v1.x, sbits, 4);  a[5]  = sflip(v1.y, sbits, 5);
        a[6]  = sflip(v1.z, sbits, 6);  a[7]  = sflip(v1.w, sbits, 7);
        a[8]  = sflip(v2.x, sbits, 8);  a[9]  = sflip(v2.y, sbits, 9);
        a[10] = sflip(v2.z, sbits, 10); a[11] = sflip(v2.w, sbits, 11);
        a[12] = sflip(v3.x, sbits, 12); a[13] = sflip(v3.y, sbits, 13);
        a[14] = sflip(v3.z, sbits, 14); a[15] = sflip(v3.w, sbits, 15);

        fwht_raw(a, lane);  // a = R = raw H(s*x); true r = R/sqrt(128)

        // fused reductions over the row's 8 lanes: ss = sum R^2, sa = sum |R|
        float ss = 0.0f, sa = 0.0f;
#pragma unroll
        for (int i = 0; i < 16; ++i) {
            ss = fmaf(a[i], a[i], ss);
            sa += fabsf(a[i]);
        }
        ss += swz_xor<1>(ss); sa += swz_xor<1>(sa);
        ss += swz_xor<2>(ss); sa += swz_xor<2>(sa);
        ss += swz_xor<4>(ss); sa += swz_xor<4>(sa);

        const float norm   = sqrtf(ss) * INV_SQRT_DIM;   // |r|
        const float t      = norm + 1e-8f;               // norm + EPS
        const float scales = (0.456f / 128.0f) * sa / t; // C * mean|u|,  u_i = R_i / t
        const float sden   = scales + 1e-8f;
        const float d      = t * sden;                   // u/sden == R/d
        const float ofac   = scales * norm * (1.0f / 128.0f);  // folds both 1/sqrt(128)

        // q = clip(round(u/sden), -8, 7)   (pack/unpack is identity)
#pragma unroll
        for (int i = 0; i < 16; ++i)
            a[i] = fminf(fmaxf(rintf(a[i] / d), -8.0f), 7.0f);

        fwht_raw(a, lane);  // raw inverse (H is involutive up to scale, folded in ofac)

        float* op = out + row * DIM + j * 16;
        float4 o;
        o.x = sflip(a[0] * ofac,  sbits, 0);  o.y = sflip(a[1] * ofac,  sbits, 1);
        o.z = sflip(a[2] * ofac,  sbits, 2);  o.w = sflip(a[3] * ofac,  sbits, 3);
        *reinterpret_cast<float4*>(op) = o;
        o.x = sflip(a[4] * ofac,  sbits, 4);  o.y = sflip(a[5] * ofac,  sbits, 5);
        o.z = sflip(a[6] * ofac,  sbits, 6);  o.w = sflip(a[7] * ofac,  sbits, 7);
        *reinterpret_cast<float4*>(op + 4) = o;
        o.x = sflip(a[8] * ofac,  sbits, 8);  o.y = sflip(a[9] * ofac,  sbits, 9);
        o.z = sflip(a[10] * ofac, sbits, 10); o.w = sflip(a[11] * ofac, sbits, 11);
        *reinterpret_cast<float4*>(op + 8) = o;
        o.x = sflip(a[12] * ofac, sbits, 12); o.y = sflip(a[13] * ofac, sbits, 13);
        o.z = sflip(a[14] * ofac, sbits, 14); o.w = sflip(a[15] * ofac, sbits, 15);
        *reinterpret_cast<float4*>(op + 12) = o;
    }
}

extern "C" void kernel_launch(void* const* d_in, const int* in_sizes, int n_in,
                              void* d_out, int out_size, void* d_ws, size_t ws_size,
                              hipStream_t stream) {
    const float* x     = (const float*)d_in[0];
    const float* signs = (const float*)d_in[1];
    float* out = (float*)d_out;
    const long long nrows = (long long)in_sizes[0] / DIM;
    turboquant_kernel<<<2048, 256, 0, stream>>>(x, signs, out, nrows);
}

// Round 3
// 105.979 us; speedup vs baseline: 1.5129x; 1.4157x over previous
//
#include <hip/hip_runtime.h>
#include <math.h>

// TurboQuantValue: sign-flip -> FWHT128 -> 4-bit quant/dequant -> FWHT128 -> sign-flip.
// Layout: 8 lanes per row, 16 elems per lane in PERMUTED order for perfect
// per-instruction coalescing: reg a[4k+i] holds element e = 32k + 4j + i
// (j = lane&7). Load/store instruction k covers a full contiguous 128B line
// per 8-lane row group. FWHT: e-bits 0,1 and 5,6 in-register; e-bits 2,3,4
// via ds_swizzle lane-XOR 1,2,4. One IEEE reciprocal per row.

#define DIM 128
#define INV_SQRT_DIM 0.08838834764831845f

template <int M>
__device__ __forceinline__ float swz_xor(float v) {
    int r = __builtin_amdgcn_ds_swizzle(__float_as_int(v), (M << 10) | 0x1F);
    return __int_as_float(r);
}

__device__ __forceinline__ float sflip(float v, unsigned sbits, int k) {
    unsigned m = ((sbits >> k) & 1u) << 31;
    return __int_as_float(__float_as_int(v) ^ m);
}

// raw (unnormalized) FWHT over 128 elems; reg-index bits cover e-bits {0,1,5,6},
// lane bits 0-2 cover e-bits {2,3,4}. Butterfly order is arbitrary.
__device__ __forceinline__ void fwht_raw(float a[16], int lane) {
#pragma unroll
    for (int h = 1; h < 16; h <<= 1) {
#pragma unroll
        for (int i = 0; i < 16; ++i) {
            if (!(i & h)) {
                float u = a[i], w = a[i + h];
                a[i] = u + w;
                a[i + h] = u - w;
            }
        }
    }
    {
        const float sgn = (lane & 1) ? -1.0f : 1.0f;
#pragma unroll
        for (int i = 0; i < 16; ++i) { float b = swz_xor<1>(a[i]); a[i] = fmaf(sgn, a[i], b); }
    }
    {
        const float sgn = (lane & 2) ? -1.0f : 1.0f;
#pragma unroll
        for (int i = 0; i < 16; ++i) { float b = swz_xor<2>(a[i]); a[i] = fmaf(sgn, a[i], b); }
    }
    {
        const float sgn = (lane & 4) ? -1.0f : 1.0f;
#pragma unroll
        for (int i = 0; i < 16; ++i) { float b = swz_xor<4>(a[i]); a[i] = fmaf(sgn, a[i], b); }
    }
}

__global__ __launch_bounds__(256) void turboquant_kernel(
    const float* __restrict__ x, const float* __restrict__ signs,
    float* __restrict__ out, long long nrows) {
    const int lane = threadIdx.x & 63;
    const int j    = lane & 7;   // lane within row; owns elems 32k + 4j + i
    const int rsub = lane >> 3;  // row within the wave's 8-row group

    // per-lane sign bitmask (1 = negative); bit (4k+i) <-> signs[32k + 4j + i]
    unsigned sbits = 0;
#pragma unroll
    for (int k = 0; k < 4; ++k) {
        float4 sv = *reinterpret_cast<const float4*>(signs + k * 32 + j * 4);
        if (sv.x < 0.5f) sbits |= 1u << (k * 4 + 0);
        if (sv.y < 0.5f) sbits |= 1u << (k * 4 + 1);
        if (sv.z < 0.5f) sbits |= 1u << (k * 4 + 2);
        if (sv.w < 0.5f) sbits |= 1u << (k * 4 + 3);
    }

    const long long waves_total = (long long)gridDim.x * 4;
    const long long wid = (long long)blockIdx.x * 4 + (threadIdx.x >> 6);

    for (long long it = wid; it * 8 < nrows; it += waves_total) {
        const long long row = it * 8 + rsub;
        const float* rp = x + row * DIM + j * 4;

        float a[16];
#pragma unroll
        for (int k = 0; k < 4; ++k) {
            float4 v = *reinterpret_cast<const float4*>(rp + k * 32);
            a[k * 4 + 0] = sflip(v.x, sbits, k * 4 + 0);
            a[k * 4 + 1] = sflip(v.y, sbits, k * 4 + 1);
            a[k * 4 + 2] = sflip(v.z, sbits, k * 4 + 2);
            a[k * 4 + 3] = sflip(v.w, sbits, k * 4 + 3);
        }

        fwht_raw(a, lane);  // a = R = raw H(s*x); true r = R/sqrt(128)

        // fused reductions over the row's 8 lanes: ss = sum R^2, sa = sum |R|
        float ss = 0.0f, sa = 0.0f;
#pragma unroll
        for (int i = 0; i < 16; ++i) {
            ss = fmaf(a[i], a[i], ss);
            sa += fabsf(a[i]);
        }
        ss += swz_xor<1>(ss); sa += swz_xor<1>(sa);
        ss += swz_xor<2>(ss); sa += swz_xor<2>(sa);
        ss += swz_xor<4>(ss); sa += swz_xor<4>(sa);

        const float norm   = sqrtf(ss) * INV_SQRT_DIM;   // |r|
        const float t      = norm + 1e-8f;               // norm + EPS
        const float scales = (0.456f / 128.0f) * sa / t; // C * mean|u|
        const float sden   = scales + 1e-8f;
        const float id     = 1.0f / (t * sden);          // u/sden == R * id
        const float ofac   = scales * norm * (1.0f / 128.0f);

        // q = clip(round(u/sden), -8, 7)   (pack/unpack is identity)
#pragma unroll
        for (int i = 0; i < 16; ++i)
            a[i] = fminf(fmaxf(rintf(a[i] * id), -8.0f), 7.0f);

        fwht_raw(a, lane);  // raw inverse; normalization folded into ofac

        float* op = out + row * DIM + j * 4;
#pragma unroll
        for (int k = 0; k < 4; ++k) {
            float4 o;
            o.x = sflip(a[k * 4 + 0] * ofac, sbits, k * 4 + 0);
            o.y = sflip(a[k * 4 + 1] * ofac, sbits, k * 4 + 1);
            o.z = sflip(a[k * 4 + 2] * ofac, sbits, k * 4 + 2);
            o.w = sflip(a[k * 4 + 3] * ofac, sbits, k * 4 + 3);
            *reinterpret_cast<float4*>(op + k * 32) = o;
        }
    }
}

extern "C" void kernel_launch(void* const* d_in, const int* in_sizes, int n_in,
                              void* d_out, int out_size, void* d_ws, size_t ws_size,
                              hipStream_t stream) {
    const float* x     = (const float*)d_in[0];
    const float* signs = (const float*)d_in[1];
    float* out = (float*)d_out;
    const long long nrows = (long long)in_sizes[0] / DIM;
    turboquant_kernel<<<2048, 256, 0, stream>>>(x, signs, out, nrows);
}